// Round 13
// baseline (50912.744 us; speedup 1.0000x reference)
//
#include <hip/hip_runtime.h>
#include <hip/hip_fp16.h>
#include <math.h>

#define NBLK 256
#define NTHR 1024

__device__ __forceinline__ float fast_rcp(float x) {
#if __has_builtin(__builtin_amdgcn_rcpf)
  return __builtin_amdgcn_rcpf(x);
#else
  return 1.f / x;
#endif
}
__device__ __forceinline__ float fast_sigmoid(float x) { return fast_rcp(1.f + __expf(-x)); }
__device__ __forceinline__ float fast_tanh(float x) { return 1.f - 2.f * fast_rcp(1.f + __expf(2.f * x)); }

union HU2 { unsigned int u; __half2 h; };
union HU4 { uint4 u; __half2 h[4]; };
__device__ __forceinline__ float2 cvt2(unsigned int u) { HU2 t; t.u = u; return __half22float2(t.h); }

__device__ __forceinline__ void sta(float* p, float v) {
  __hip_atomic_store(p, v, __ATOMIC_RELAXED, __HIP_MEMORY_SCOPE_AGENT);
}
__device__ __forceinline__ float lda(const float* p) {
  return __hip_atomic_load(p, __ATOMIC_RELAXED, __HIP_MEMORY_SCOPE_AGENT);
}
__device__ __forceinline__ int ldai(const int* p) {
  return __hip_atomic_load(p, __ATOMIC_RELAXED, __HIP_MEMORY_SCOPE_AGENT);
}
__device__ __forceinline__ void ntst(float* p, float v) { __builtin_nontemporal_store(v, p); }

struct Params {
  const float *enc, *pre_w1, *pre_w2, *attn_bi, *attn_bh;
  const float *q_w, *k_w, *score_w, *score_b, *conv_w, *loc_w, *loc_b;
  const float *out_bi, *out_bh, *dec_b, *gate_b;
  const float *attn_wi, *attn_wh, *out_wi, *out_wh, *dec_w, *gate_w;
  const int *text_lens, *mel_lens;
  __half *hkeys, *gw1T, *gw2T, *decT, *pre1T, *pre2T, *gateh, *locwh, *qwT;
  float *hA, *hO, *attw, *attcum, *decin, *ebuf, *zpart, *ctxacc, *ctxacc2, *stateZ;
  float *qbuf;
  int *done, *zdone, *hAdone, *qdone, *adone;
  float *out_mel, *out_gate, *out_attn, *out_mask;
};

// ---------------- prep: keys GEMM (fp16 out) ----------------
__global__ __launch_bounds__(512) void k_keys(Params p) {
  __shared__ float sA[16][132];
  __shared__ float sB[16][68];
  int tid = threadIdx.x;
  int row0 = blockIdx.x * 128, col0 = blockIdx.y * 64;
  float acc[4][4] = {};
  int r = tid >> 2, kq = tid & 3;
  int tx = tid & 15, ty = tid >> 4;
  for (int k0 = 0; k0 < 1024; k0 += 16) {
    __syncthreads();
    float4 a4 = *(const float4*)(p.enc + (size_t)(row0 + r) * 1024 + k0 + kq * 4);
    sA[kq * 4 + 0][r] = a4.x; sA[kq * 4 + 1][r] = a4.y;
    sA[kq * 4 + 2][r] = a4.z; sA[kq * 4 + 3][r] = a4.w;
    if (tid < 256) {
      int kb = tid >> 4, nb = (tid & 15) * 4;
      float4 b4 = *(const float4*)(p.k_w + (size_t)(k0 + kb) * 512 + col0 + nb);
      sB[kb][nb + 0] = b4.x; sB[kb][nb + 1] = b4.y;
      sB[kb][nb + 2] = b4.z; sB[kb][nb + 3] = b4.w;
    }
    __syncthreads();
#pragma unroll
    for (int k = 0; k < 16; k++) {
      float ar[4], br[4];
#pragma unroll
      for (int i = 0; i < 4; i++) { ar[i] = sA[k][ty * 4 + i]; br[i] = sB[k][tx * 4 + i]; }
#pragma unroll
      for (int i = 0; i < 4; i++)
#pragma unroll
        for (int j = 0; j < 4; j++) acc[i][j] = fmaf(ar[i], br[j], acc[i][j]);
    }
  }
#pragma unroll
  for (int i = 0; i < 4; i++)
#pragma unroll
    for (int j = 0; j < 4; j++)
      p.hkeys[(size_t)(row0 + ty * 4 + i) * 512 + col0 + tx * 4 + j] = __float2half(acc[i][j]);
}

// ---------------- prep: repack weights + zero state/flags ----------------
__global__ __launch_bounds__(256) void k_repack(Params p) {
  const int gsz = gridDim.x * 256;
  const int t0 = blockIdx.x * 256 + threadIdx.x;
  for (int i = t0; i < 1280 * 512; i += gsz) {
    int r = i >> 9, u = i & 511;
    const float* src = (r < 768) ? p.attn_wi + (size_t)r * 1536 : p.attn_wh + (size_t)(r - 768) * 1536;
    __half2* d = (__half2*)(p.gw1T + ((size_t)i << 2));
    d[0] = __halves2half2(__float2half(src[u]), __float2half(src[512 + u]));
    d[1] = __halves2half2(__float2half(src[1024 + u]), __float2half(0.f));
  }
  for (int i = t0; i < 1536 * 512; i += gsz) {
    int r = i >> 9, u = i & 511;
    const float* src = (r < 1024) ? p.out_wi + (size_t)r * 1536 : p.out_wh + (size_t)(r - 1024) * 1536;
    __half2* d = (__half2*)(p.gw2T + ((size_t)i << 2));
    d[0] = __halves2half2(__float2half(src[u]), __float2half(src[512 + u]));
    d[1] = __halves2half2(__float2half(src[1024 + u]), __float2half(0.f));
  }
  for (int i = t0; i < 512 * 512; i += gsz) {
    int k = i >> 9, a = i & 511;
    p.qwT[(size_t)a * 512 + k] = __float2half(p.q_w[(size_t)k * 512 + a]);
  }
  for (int i = t0; i < 1024 * 128; i += gsz) {
    int k = i >> 7, m = i & 127;
    p.decT[(size_t)m * 1024 + k] = __float2half(p.dec_w[(size_t)k * 128 + m]);
  }
  for (int i = t0; i < 1024; i += gsz) p.gateh[i] = __float2half(p.gate_w[i]);
  for (int i = t0; i < 16384; i += gsz) p.locwh[i] = __float2half(p.loc_w[i]);
  for (int i = t0; i < 128 * 256; i += gsz) {
    int m = i >> 8, pc = i & 255;
    p.pre1T[(size_t)pc * 128 + m] = __float2half(p.pre_w1[(size_t)m * 256 + pc]);
  }
  for (int i = t0; i < 256 * 256; i += gsz) {
    int k = i >> 8, pc = i & 255;
    p.pre2T[(size_t)pc * 256 + k] = __float2half(p.pre_w2[(size_t)k * 256 + pc]);
  }
  for (int i = t0; i < 106496; i += gsz) p.stateZ[i] = 0.f;
  for (int i = t0; i < 16384; i += gsz) p.ctxacc[i] = 0.f;
  for (int i = t0; i < 16384; i += gsz) p.ctxacc2[i] = 0.f;
  for (int i = t0; i < 2048; i += gsz) p.hAdone[i] = 0;   // whole flag region
  for (int i = t0; i < 12800; i += gsz) {
    int b = i / 400, t = i - b * 400;
    p.out_mask[i] = (t > p.mel_lens[b]) ? 1.f : 0.f;
  }
}

struct SMemMega {
  __half keysL[64 * 512];   // persistent P2 keys tile (64 KB)
  float ctxL[4][520];       // persistent ctx (this step)
  float hA2[4][520];        // persistent hA (staged in P2 tail; = hA_prev for next P1f)
  float hO2[4][520];        // persistent hO (refilled at P3 tail with hO_next)
  float decinL[4][264];     // persistent decin carry (local S6 -> next P1f)
  float invZ[4];
  union {
    struct { float pad[1056]; float4 part4[16][64]; } gr;  // pad aligns part4 past decin region
    struct { float locS[64][33]; float aw[94]; float ac[94]; float hA_s[512];
             float qS[512]; float qp2[16][64]; float cpred[8][512]; float eS[64]; } s3;
    struct { float red[4][264]; float mel[4][132]; float p1[4][264]; } s6;
  } u;
};

// GRU partial accumulation over interleaved rows r = ks + 16*j, j in [j0,j1).
__device__ __forceinline__ void gchunk(const uint2* __restrict__ w,
                                       const float* __restrict__ x, int ks,
                                       int j0, int j1,
                                       float& a0, float& a1, float& a2) {
#pragma unroll 8
  for (int j = j0; j < j1; ++j) {
    uint2 wv = w[(size_t)j << 13];          // + j*16 rows * 512
    float xv = x[ks + (j << 4)];
    float2 f0 = cvt2(wv.x);
    float nf = cvt2(wv.y).x;
    a0 = fmaf(xv, f0.x, a0);
    a1 = fmaf(xv, f0.y, a1);
    a2 = fmaf(xv, nf, a2);
  }
}

__global__ __launch_bounds__(NTHR) void mega(Params p) {
  __shared__ SMemMega sm;
  const int blk = blockIdx.x, tid = threadIdx.x;
  const int ug = blk & 31, bg = blk >> 5, b0 = bg * 4;       // GRU identity
  const int bS = blk & 31, t8 = blk >> 5, t0g = t8 << 6;     // attention identity
  const int bgS = bS >> 2;                                   // bg owning batch bS

  const int u_ = tid & 15, b2_ = (tid >> 4) & 3, ks_ = tid >> 6;
  const int uG_ = (ug << 4) + u_;
  const uint2* w1 = (const uint2*)p.gw1T + ((size_t)ks_ << 9) + uG_;
  const uint2* w2 = (const uint2*)p.gw2T + ((size_t)ks_ << 9) + uG_;

  // ---- one-time: load keys tile into LDS, zero persistent LDS ----
  {
    const uint4* src = (const uint4*)(p.hkeys + (((size_t)(bS << 9) + t0g) << 9));
    uint4* dst = (uint4*)sm.keysL;
    for (int i = tid; i < 4096; i += NTHR) dst[i] = src[i];
    for (int i = tid; i < 2048; i += NTHR) {
      sm.ctxL[i >> 9][i & 511] = 0.f;
      sm.hA2[i >> 9][i & 511] = 0.f;
      sm.hO2[i >> 9][i & 511] = 0.f;
    }
    for (int i = tid; i < 1024; i += NTHR) sm.decinL[i >> 8][i & 255] = 0.f;
  }
  __syncthreads();

  // GRU1 partial accumulators carried from P3 (prev step) into P1f (this step).
  float g1r = 0.f, g1z = 0.f, g1ni = 0.f, g1nh = 0.f;

#pragma clang loop unroll(disable)
  for (int step = 0; step < 400; step++) {
    const int par = step & 1;
    float* hA_next = p.hA + (par ^ 1) * 16384;
    float* hO_next = p.hO + (par ^ 1) * 16384;
    float* cCur = par ? p.ctxacc2 : p.ctxacc;
    float* cNxt = par ? p.ctxacc : p.ctxacc2;

    // GRU2 partial accumulators for THIS step
    float r2 = 0.f, z2 = 0.f, ni2 = 0.f, nh2 = 0.f;

    // ======== P1f: pure-LDS GRU1 finish + hA (no waits, no global staging) ========
    {
      gchunk(w1, &sm.decinL[b2_][0], ks_, 0, 16, g1r, g1z, g1ni);  // decin rows 0..255
      sm.u.gr.part4[ks_][(u_ << 2) + b2_] = make_float4(g1r, g1z, g1ni, g1nh);
      __syncthreads();
      if (tid < 64) {
        int uu = tid >> 2, bb2 = tid & 3;
        float4 s = make_float4(0.f, 0.f, 0.f, 0.f);
#pragma unroll
        for (int l = 0; l < 16; l++) {
          float4 v = sm.u.gr.part4[l][(uu << 2) + bb2];
          s.x += v.x; s.y += v.y; s.z += v.z; s.w += v.w;
        }
        int uGf = (ug << 4) + uu;
        float r = fast_sigmoid(s.x + p.attn_bi[uGf] + p.attn_bh[uGf]);
        float z = fast_sigmoid(s.y + p.attn_bi[512 + uGf] + p.attn_bh[512 + uGf]);
        float n = fast_tanh(s.z + p.attn_bi[1024 + uGf] + r * (s.w + p.attn_bh[1024 + uGf]));
        float hv = sm.hA2[bb2][uGf];                 // hA_prev held locally
        sta(&hA_next[((b0 + bb2) << 9) + uGf], (1.f - z) * n + z * hv);
      }
      asm volatile("s_waitcnt vmcnt(0)" ::: "memory");
      if (tid == 0) atomicAdd(&p.hAdone[bg * 16], 1);   // 32/step per bg
      // GRU2 hO-part (rows 1024..1535) from hO2 (filled at P3(s-1) tail)
      gchunk(w2, &sm.hO2[b2_][0] - 1024, ks_, 64, 96, r2, z2, nh2);
    }

    // ======== P2: adone gate + staging/conv + q-slice + loc-acc + score + ctx ========
    {
      __syncthreads();   // union gr -> s3 transition
      if (step > 0) {
        if (tid == 0) {
          while (ldai(&p.adone[bS * 16]) < 8 * step)    // attw(s-1) ready
            __builtin_amdgcn_s_sleep(2);
        }
        __syncthreads();
      }
      for (int j = tid; j < 94; j += NTHR) {
        int pp = t0g - 15 + j;
        bool ok = (unsigned)pp < 512u;
        sm.u.s3.aw[j] = ok ? lda(&p.attw[(bS << 9) + pp]) : 0.f;
        sm.u.s3.ac[j] = ok ? lda(&p.attcum[(bS << 9) + pp]) : 0.f;
      }
      if (t8 == 0) {
        for (int i = tid; i < 512; i += NTHR) sta(&cNxt[(bS << 9) + i], 0.f);
      }
      __syncthreads();
      const int tlen = p.text_lens[bS];
      for (int i = tid; i < 2048; i += NTHR) {
        int tt = i >> 5, f = i & 31;
        const float* w0 = p.conv_w + f * 62;
        float a = 0.f;
#pragma unroll
        for (int k = 0; k < 31; k++)
          a = fmaf(w0[k], sm.u.s3.aw[tt + k], fmaf(w0[31 + k], sm.u.s3.ac[tt + k], a));
        sm.u.s3.locS[tt][f] = a;
      }
      if (tid == 0) {
        while (ldai(&p.hAdone[bgS * 16]) < 32 * (step + 1))
          __builtin_amdgcn_s_sleep(2);
      }
      __syncthreads();
      if (tid < 512) sm.u.s3.hA_s[tid] = lda(&hA_next[(bS << 9) + tid]);
      __syncthreads();
      // --- q-slice GEMV: a in [t0g, t0g+64), k split over 16 groups ---
      {
        int a = tid & 63, ks = tid >> 6;   // ks in 0..15
        const HU4* qp = (const HU4*)(p.qwT + (size_t)(t0g + a) * 512 + ks * 32);
        float q0 = 0.f, q1 = 0.f;
#pragma unroll
        for (int it = 0; it < 4; it++) {
          HU4 raw = qp[it];
          int kb = ks * 32 + it * 8;
#pragma unroll
          for (int h2 = 0; h2 < 4; h2++) {
            float2 w = __half22float2(raw.h[h2]);
            q0 = fmaf(sm.u.s3.hA_s[kb + h2 * 2], w.x, q0);
            q1 = fmaf(sm.u.s3.hA_s[kb + h2 * 2 + 1], w.y, q1);
          }
        }
        sm.u.s3.qp2[ks][a] = q0 + q1;
      }
      __syncthreads();
      if (tid < 64) {
        float s = 0.f;
#pragma unroll
        for (int l = 0; l < 16; l++) s += sm.u.s3.qp2[l][tid];
        sta(&p.qbuf[(bS << 9) + t0g + tid], s + p.loc_b[t0g + tid]);
      }
      if (tid == 0) {
        asm volatile("s_waitcnt vmcnt(0)" ::: "memory");
        atomicAdd(&p.qdone[bS * 16], 1);
      }
      // --- loc-only score accumulation (overlaps other blocks' q-slices) ---
      const int lane = tid & 63, wv = tid >> 6;
      float acc[4][8] = {};
#pragma unroll 4
      for (int f = 0; f < 32; f++) {
        HU4 rw; rw.u = *(const uint4*)(p.locwh + (size_t)f * 512 + lane * 8);
        float2 w0 = __half22float2(rw.h[0]), w1 = __half22float2(rw.h[1]);
        float2 w2v = __half22float2(rw.h[2]), w3 = __half22float2(rw.h[3]);
#pragma unroll
        for (int j = 0; j < 4; j++) {
          float lf = sm.u.s3.locS[wv * 4 + j][f];
          acc[j][0] = fmaf(lf, w0.x, acc[j][0]); acc[j][1] = fmaf(lf, w0.y, acc[j][1]);
          acc[j][2] = fmaf(lf, w1.x, acc[j][2]); acc[j][3] = fmaf(lf, w1.y, acc[j][3]);
          acc[j][4] = fmaf(lf, w2v.x, acc[j][4]); acc[j][5] = fmaf(lf, w2v.y, acc[j][5]);
          acc[j][6] = fmaf(lf, w3.x, acc[j][6]); acc[j][7] = fmaf(lf, w3.y, acc[j][7]);
        }
      }
      if (tid == 0) {
        while (ldai(&p.qdone[bS * 16]) < 8 * (step + 1))
          __builtin_amdgcn_s_sleep(2);
      }
      __syncthreads();
      if (tid < 512) sm.u.s3.qS[tid] = lda(&p.qbuf[(bS << 9) + tid]);
      __syncthreads();
      float4 qA = *(const float4*)&sm.u.s3.qS[lane * 8];
      float4 qB = *(const float4*)&sm.u.s3.qS[lane * 8 + 4];
#pragma unroll
      for (int j = 0; j < 4; j++) {
        int tL = wv * 4 + j;
        HU4 raw; raw.u = *(const uint4*)&sm.keysL[tL * 512 + lane * 8];
        float2 k0 = __half22float2(raw.h[0]), k1 = __half22float2(raw.h[1]);
        float2 k2 = __half22float2(raw.h[2]), k3 = __half22float2(raw.h[3]);
        acc[j][0] += qA.x + k0.x; acc[j][1] += qA.y + k0.y;
        acc[j][2] += qA.z + k1.x; acc[j][3] += qA.w + k1.y;
        acc[j][4] += qB.x + k2.x; acc[j][5] += qB.y + k2.y;
        acc[j][6] += qB.z + k3.x; acc[j][7] += qB.w + k3.y;
      }
      float4 sA = *(const float4*)(p.score_w + lane * 8);
      float4 sB = *(const float4*)(p.score_w + lane * 8 + 4);
      float sbias = p.score_b[0];
      float e_reg[4];
#pragma unroll
      for (int j = 0; j < 4; j++) {
        float pv = fast_tanh(acc[j][0]) * sA.x + fast_tanh(acc[j][1]) * sA.y +
                   fast_tanh(acc[j][2]) * sA.z + fast_tanh(acc[j][3]) * sA.w +
                   fast_tanh(acc[j][4]) * sB.x + fast_tanh(acc[j][5]) * sB.y +
                   fast_tanh(acc[j][6]) * sB.z + fast_tanh(acc[j][7]) * sB.w;
#pragma unroll
        for (int off = 32; off > 0; off >>= 1) pv += __shfl_xor(pv, off, 64);
        int t = t0g + wv * 4 + j;
        e_reg[j] = (t > tlen) ? 0.f : __expf(pv + sbias);
      }
      if (lane == 0) {
#pragma unroll
        for (int j = 0; j < 4; j++) sm.u.s3.eS[wv * 4 + j] = e_reg[j];
      }
      float cp[8] = {0.f, 0.f, 0.f, 0.f, 0.f, 0.f, 0.f, 0.f};
#pragma unroll
      for (int j = 0; j < 4; j++) {
        int tL = wv * 4 + j;
        HU4 raw; raw.u = *(const uint4*)&sm.keysL[tL * 512 + lane * 8];
        float2 k0 = __half22float2(raw.h[0]), k1 = __half22float2(raw.h[1]);
        float2 k2 = __half22float2(raw.h[2]), k3 = __half22float2(raw.h[3]);
        float e = e_reg[j];
        cp[0] = fmaf(e, k0.x, cp[0]); cp[1] = fmaf(e, k0.y, cp[1]);
        cp[2] = fmaf(e, k1.x, cp[2]); cp[3] = fmaf(e, k1.y, cp[3]);
        cp[4] = fmaf(e, k2.x, cp[4]); cp[5] = fmaf(e, k2.y, cp[5]);
        cp[6] = fmaf(e, k3.x, cp[6]); cp[7] = fmaf(e, k3.y, cp[7]);
      }
      __syncthreads();
      if (wv < 8) {
        float4* r0 = (float4*)&sm.u.s3.cpred[wv][lane * 8];
        r0[0] = make_float4(cp[0], cp[1], cp[2], cp[3]);
        r0[1] = make_float4(cp[4], cp[5], cp[6], cp[7]);
      }
      __syncthreads();
      if (wv >= 8) {
        float* r0 = &sm.u.s3.cpred[wv - 8][lane * 8];
#pragma unroll
        for (int i = 0; i < 8; i++) r0[i] += cp[i];
      }
      __syncthreads();
      if (tid < 512) {
        float s = 0.f;
#pragma unroll
        for (int j = 0; j < 8; j++) s += sm.u.s3.cpred[j][tid];
        atomicAdd(&cCur[(bS << 9) + tid], s);
      }
      if (tid < 64) {
        float e = sm.u.s3.eS[tid];
        sta(&p.ebuf[(bS << 9) + t0g + tid], e);
        float z = e;
#pragma unroll
        for (int off = 32; off > 0; off >>= 1) z += __shfl_xor(z, off, 64);
        if (tid == 0) sta(&p.zpart[bS * 8 + t8], z);
      }
      if (tid < 512 && (tid & 63) == 0) {
        asm volatile("s_waitcnt vmcnt(0)" ::: "memory");
        atomicAdd(&p.zdone[bgS * 16], 1);   // target 256 per bg per step
      }
      // ---- stage hA2 (own bg) + GRU2 hA-part ----
      if (tid == 0) {
        while (ldai(&p.hAdone[bg * 16]) < 32 * (step + 1))
          __builtin_amdgcn_s_sleep(2);
      }
      __syncthreads();
      for (int i = tid; i < 2048; i += NTHR)
        sm.hA2[i >> 9][i & 511] = lda(&hA_next[((b0 + (i >> 9)) << 9) + (i & 511)]);
      __syncthreads();
      gchunk(w2, &sm.hA2[b2_][0], ks_, 0, 32, r2, z2, ni2);   // rows 0..511
    }

    // ======== P3: ctx + GRU2 finish + attw + GRU1-pre + replicated local S6 ========
    {
      if (tid == 0) {
        while (ldai(&p.zdone[bg * 16]) < 256 * (step + 1))
          __builtin_amdgcn_s_sleep(2);
      }
      __syncthreads();
      if (tid < 4) {
        float Z = 0.f;
#pragma unroll
        for (int j = 0; j < 8; j++) Z += lda(&p.zpart[(b0 + tid) * 8 + j]);
        sm.invZ[tid] = fast_rcp(Z);
      }
      __syncthreads();
      for (int i = tid; i < 2048; i += NTHR) {
        int b2 = i >> 9, a = i & 511;
        sm.ctxL[b2][a] = lda(&cCur[((b0 + b2) << 9) + a]) * sm.invZ[b2];
      }
      __syncthreads();
      gchunk(w2, &sm.ctxL[b2_][0] - 512, ks_, 32, 64, r2, z2, ni2);  // ctx rows
      sm.u.gr.part4[ks_][(u_ << 2) + b2_] = make_float4(r2, z2, ni2, nh2);
      __syncthreads();
      if (tid < 64) {
        int uu = tid >> 2, bb2 = tid & 3;
        float4 s = make_float4(0.f, 0.f, 0.f, 0.f);
#pragma unroll
        for (int l = 0; l < 16; l++) {
          float4 v = sm.u.gr.part4[l][(uu << 2) + bb2];
          s.x += v.x; s.y += v.y; s.z += v.z; s.w += v.w;
        }
        int uGf = (ug << 4) + uu;
        float r = fast_sigmoid(s.x + p.out_bi[uGf] + p.out_bh[uGf]);
        float z = fast_sigmoid(s.y + p.out_bi[512 + uGf] + p.out_bh[512 + uGf]);
        float n = fast_tanh(s.z + p.out_bi[1024 + uGf] + r * (s.w + p.out_bh[1024 + uGf]));
        float hv = sm.hO2[bb2][uGf];
        sta(&hO_next[((b0 + bb2) << 9) + uGf], (1.f - z) * n + z * hv);
      }
      asm volatile("s_waitcnt vmcnt(0)" ::: "memory");
      if (tid == 0) atomicAdd(&p.done[bg * 16], 1);   // 32/step per bg
      // ---- attw/attcum update for batch b0+(ug-4): off the S6 path ----
      if (ug >= 4 && ug < 8) {
        const int bj = ug - 4, bb = b0 + bj;
        if (tid < 512) {
          float v = lda(&p.ebuf[(bb << 9) + tid]) * sm.invZ[bj];
          sta(&p.attw[(bb << 9) + tid], v);
          float oc = lda(&p.attcum[(bb << 9) + tid]);
          sta(&p.attcum[(bb << 9) + tid], oc + v);
          ntst(&p.out_attn[(size_t)bb * 204800 + (size_t)step * 512 + tid], v);
        }
        if (tid < 512 && (tid & 63) == 0) {
          asm volatile("s_waitcnt vmcnt(0)" ::: "memory");
          atomicAdd(&p.adone[bb * 16], 1);   // 8/step per batch
        }
      }
      // ---- GRU1 pre-accumulation for NEXT step (overlaps done stragglers) ----
      g1r = 0.f; g1z = 0.f; g1ni = 0.f; g1nh = 0.f;
      if (step < 399) {
        gchunk(w1, &sm.ctxL[b2_][0] - 256, ks_, 16, 48, g1r, g1z, g1ni);
        gchunk(w1, &sm.hA2[b2_][0] - 768, ks_, 48, 80, g1r, g1z, g1nh);
      }
      // ---- replicated local S6: every block, 4 batches, decin -> LDS ----
      if (tid == 0) {
        while (ldai(&p.done[bg * 16]) < 32 * (step + 1))
          __builtin_amdgcn_s_sleep(2);
      }
      __syncthreads();
      for (int i = tid; i < 2048; i += NTHR)
        sm.hO2[i >> 9][i & 511] = lda(&hO_next[((b0 + (i >> 9)) << 9) + (i & 511)]);
      __syncthreads();
      // dec GEMV: 1024 threads = (kh, b, m); x reads are wave-uniform broadcasts
      {
        int m = tid & 127, b = (tid >> 7) & 3, kh = tid >> 9;
        const HU4* dp = (const HU4*)(p.decT + (size_t)m * 1024 + kh * 512);
        const float* xb = kh ? &sm.ctxL[b][0] : &sm.hO2[b][0];
        float a = 0.f;
#pragma unroll 8
        for (int it = 0; it < 64; it++) {
          HU4 raw = dp[it];
          int kb = it * 8;
#pragma unroll
          for (int h2 = 0; h2 < 4; h2++) {
            float2 w = __half22float2(raw.h[h2]);
            a = fmaf(xb[kb + h2 * 2], w.x, a);
            a = fmaf(xb[kb + h2 * 2 + 1], w.y, a);
          }
        }
        sm.u.s6.red[b][kh * 128 + m] = a;
      }
      __syncthreads();
      if (tid < 512) {
        int b = tid >> 7, m = tid & 127;
        float mv = p.dec_b[m] + sm.u.s6.red[b][m] + sm.u.s6.red[b][128 + m];
        sm.u.s6.mel[b][m] = mv;
        if (ug < 4 && b == ug) {
          int bb = b0 + b;
          bool masked = step > p.mel_lens[bb];
          ntst(&p.out_mel[(size_t)bb * 51200 + (size_t)step * 128 + m], masked ? 0.f : mv);
        }
      } else if (ug < 4 && (tid >> 6) == 15) {
        // gate: one wave (own batch), shfl reduce, no LDS scratch
        int l = tid & 63;
        float g = 0.f;
#pragma unroll
        for (int j = 0; j < 8; j++) {
          int t = l + j * 64;
          g = fmaf(sm.hO2[ug][t], __half2float(p.gateh[t]), g);
          g = fmaf(sm.ctxL[ug][t], __half2float(p.gateh[512 + t]), g);
        }
#pragma unroll
        for (int off = 32; off > 0; off >>= 1) g += __shfl_xor(g, off, 64);
        if (l == 0) {
          int bb = b0 + ug;
          bool masked = step > p.mel_lens[bb];
          ntst(&p.out_gate[bb * 400 + step], masked ? 1000.f : (g + p.gate_b[0]));
        }
      }
      __syncthreads();
      // prenet1: 1024 threads = (b, pc); mel reads broadcast per wave
      {
        int pc = tid & 255, b = tid >> 8;
        const HU4* wp = (const HU4*)(p.pre1T + (size_t)pc * 128);
        float a = 0.f;
#pragma unroll
        for (int it = 0; it < 16; it++) {
          HU4 raw = wp[it];
          int kb = it * 8;
#pragma unroll
          for (int h2 = 0; h2 < 4; h2++) {
            float2 w = __half22float2(raw.h[h2]);
            a = fmaf(sm.u.s6.mel[b][kb + h2 * 2], w.x, a);
            a = fmaf(sm.u.s6.mel[b][kb + h2 * 2 + 1], w.y, a);
          }
        }
        sm.u.s6.p1[b][pc] = fmaxf(a, 0.f);
      }
      __syncthreads();
      // prenet2: 1024 threads = (b, pc); p1 reads broadcast per wave
      {
        int pc = tid & 255, b = tid >> 8;
        const HU4* wp = (const HU4*)(p.pre2T + (size_t)pc * 256);
        float a = 0.f;
#pragma unroll 8
        for (int it = 0; it < 32; it++) {
          HU4 raw = wp[it];
          int kb = it * 8;
#pragma unroll
          for (int h2 = 0; h2 < 4; h2++) {
            float2 w = __half22float2(raw.h[h2]);
            a = fmaf(sm.u.s6.p1[b][kb + h2 * 2], w.x, a);
            a = fmaf(sm.u.s6.p1[b][kb + h2 * 2 + 1], w.y, a);
          }
        }
        sm.decinL[b][pc] = fmaxf(a, 0.f);
      }
      __syncthreads();   // decinL/hO2 ready for next P1f
    }
  }
}

extern "C" void kernel_launch(void* const* d_in, const int* in_sizes, int n_in,
                              void* d_out, int out_size, void* d_ws, size_t ws_size,
                              hipStream_t stream) {
  Params p;
  p.enc       = (const float*)d_in[0];
  p.text_lens = (const int*)d_in[2];
  p.mel_lens  = (const int*)d_in[3];
  p.pre_w1    = (const float*)d_in[5];
  p.pre_w2    = (const float*)d_in[6];
  p.attn_wi   = (const float*)d_in[7];
  p.attn_wh   = (const float*)d_in[8];
  p.attn_bi   = (const float*)d_in[9];
  p.attn_bh   = (const float*)d_in[10];
  p.q_w       = (const float*)d_in[11];
  p.k_w       = (const float*)d_in[12];
  p.score_w   = (const float*)d_in[13];
  p.score_b   = (const float*)d_in[14];
  p.conv_w    = (const float*)d_in[15];
  p.loc_w     = (const float*)d_in[16];
  p.loc_b     = (const float*)d_in[17];
  p.out_wi    = (const float*)d_in[18];
  p.out_wh    = (const float*)d_in[19];
  p.out_bi    = (const float*)d_in[20];
  p.out_bh    = (const float*)d_in[21];
  p.dec_w     = (const float*)d_in[22];
  p.dec_b     = (const float*)d_in[23];
  p.gate_w    = (const float*)d_in[24];
  p.gate_b    = (const float*)d_in[25];

  float* ws = (float*)d_ws;
  p.hkeys  = (__half*)(ws);                    // 8,388,608 halfs
  p.gw1T   = (__half*)(ws + 4194304);
  p.gw2T   = (__half*)(ws + 5505024);
  p.decT   = (__half*)(ws + 7077888);
  p.pre1T  = (__half*)(ws + 7143424);
  p.pre2T  = (__half*)(ws + 7159808);
  p.gateh  = (__half*)(ws + 7192576);
  p.locwh  = (__half*)(ws + 7193088);
  p.qwT    = (__half*)(ws + 7201280);
  p.hA     = ws + 7332352;
  p.hO     = ws + 7365120;
  p.attw   = ws + 7397888;
  p.attcum = ws + 7414272;
  p.decin  = ws + 7430656;                     // unused now (kept zeroed)
  p.stateZ = p.hA;                             // zero region: hA,hO,attw,attcum,decin = 106,496
  p.ebuf   = ws + 7438848;
  p.zpart  = ws + 7455232;
  p.ctxacc = ws + 7455488;                     // 16384
  p.ctxacc2 = ws + 7472416;                    // 16384
  int* fb  = (int*)(ws + 7488800);             // 2048-int flag region (zeroed via hAdone)
  p.hAdone = fb;                               // per-bg x16
  p.zdone  = fb + 128;                         // per-bg x16
  p.done   = fb + 256;                         // per-bg x16
  p.qdone  = fb + 512;                         // per-batch x16
  p.adone  = fb + 1024;                        // per-batch x16
  p.qbuf   = ws + 7490848;                     // 16384 floats
  float* out = (float*)d_out;
  p.out_mel  = out;
  p.out_gate = out + 1638400;
  p.out_attn = out + 1651200;
  p.out_mask = out + 8204800;

  k_repack<<<2048, 256, 0, stream>>>(p);
  k_keys<<<dim3(128, 8), 512, 0, stream>>>(p);
  void* args[] = { (void*)&p };
  hipLaunchCooperativeKernel((const void*)mega, dim3(NBLK), dim3(NTHR), args, 0, stream);
}

// Round 16
// 35212.292 us; speedup vs baseline: 1.4459x; 1.4459x over previous
//
#include <hip/hip_runtime.h>
#include <hip/hip_fp16.h>
#include <math.h>

#define NBLK 256
#define NTHR 1024

__device__ __forceinline__ float fast_rcp(float x) {
#if __has_builtin(__builtin_amdgcn_rcpf)
  return __builtin_amdgcn_rcpf(x);
#else
  return 1.f / x;
#endif
}
__device__ __forceinline__ float fast_sigmoid(float x) { return fast_rcp(1.f + __expf(-x)); }
__device__ __forceinline__ float fast_tanh(float x) { return 1.f - 2.f * fast_rcp(1.f + __expf(2.f * x)); }

union HU2 { unsigned int u; __half2 h; };
union HU4 { uint4 u; __half2 h[4]; };
__device__ __forceinline__ float2 cvt2(unsigned int u) { HU2 t; t.u = u; return __half22float2(t.h); }

__device__ __forceinline__ void sta(float* p, float v) {
  __hip_atomic_store(p, v, __ATOMIC_RELAXED, __HIP_MEMORY_SCOPE_AGENT);
}
__device__ __forceinline__ float lda(const float* p) {
  return __hip_atomic_load(p, __ATOMIC_RELAXED, __HIP_MEMORY_SCOPE_AGENT);
}
__device__ __forceinline__ int ldai(const int* p) {
  return __hip_atomic_load(p, __ATOMIC_RELAXED, __HIP_MEMORY_SCOPE_AGENT);
}
__device__ __forceinline__ void ntst(float* p, float v) { __builtin_nontemporal_store(v, p); }

struct Params {
  const float *enc, *pre_w1, *pre_w2, *attn_bi, *attn_bh;
  const float *q_w, *k_w, *score_w, *score_b, *conv_w, *loc_w, *loc_b;
  const float *out_bi, *out_bh, *dec_b, *gate_b;
  const float *attn_wi, *attn_wh, *out_wi, *out_wh, *dec_w, *gate_w;
  const int *text_lens, *mel_lens;
  __half *hkeys, *gw1T, *gw2T, *decT, *pre1T, *pre2T, *gateh, *locwh, *qwT;
  float *hA, *hO, *attw, *attcum, *decin, *ebuf, *zpart, *ctxacc, *ctxacc2, *stateZ;
  float *qbuf;
  int *done, *zdone, *done2, *hAdone, *qdone;
  float *out_mel, *out_gate, *out_attn, *out_mask;
};

// ---------------- prep: keys GEMM (fp16 out) ----------------
__global__ __launch_bounds__(512) void k_keys(Params p) {
  __shared__ float sA[16][132];
  __shared__ float sB[16][68];
  int tid = threadIdx.x;
  int row0 = blockIdx.x * 128, col0 = blockIdx.y * 64;
  float acc[4][4] = {};
  int r = tid >> 2, kq = tid & 3;
  int tx = tid & 15, ty = tid >> 4;
  for (int k0 = 0; k0 < 1024; k0 += 16) {
    __syncthreads();
    float4 a4 = *(const float4*)(p.enc + (size_t)(row0 + r) * 1024 + k0 + kq * 4);
    sA[kq * 4 + 0][r] = a4.x; sA[kq * 4 + 1][r] = a4.y;
    sA[kq * 4 + 2][r] = a4.z; sA[kq * 4 + 3][r] = a4.w;
    if (tid < 256) {
      int kb = tid >> 4, nb = (tid & 15) * 4;
      float4 b4 = *(const float4*)(p.k_w + (size_t)(k0 + kb) * 512 + col0 + nb);
      sB[kb][nb + 0] = b4.x; sB[kb][nb + 1] = b4.y;
      sB[kb][nb + 2] = b4.z; sB[kb][nb + 3] = b4.w;
    }
    __syncthreads();
#pragma unroll
    for (int k = 0; k < 16; k++) {
      float ar[4], br[4];
#pragma unroll
      for (int i = 0; i < 4; i++) { ar[i] = sA[k][ty * 4 + i]; br[i] = sB[k][tx * 4 + i]; }
#pragma unroll
      for (int i = 0; i < 4; i++)
#pragma unroll
        for (int j = 0; j < 4; j++) acc[i][j] = fmaf(ar[i], br[j], acc[i][j]);
    }
  }
#pragma unroll
  for (int i = 0; i < 4; i++)
#pragma unroll
    for (int j = 0; j < 4; j++)
      p.hkeys[(size_t)(row0 + ty * 4 + i) * 512 + col0 + tx * 4 + j] = __float2half(acc[i][j]);
}

// ---------------- prep: repack weights + zero state/flags ----------------
__global__ __launch_bounds__(256) void k_repack(Params p) {
  const int gsz = gridDim.x * 256;
  const int t0 = blockIdx.x * 256 + threadIdx.x;
  for (int i = t0; i < 1280 * 512; i += gsz) {
    int r = i >> 9, u = i & 511;
    const float* src = (r < 768) ? p.attn_wi + (size_t)r * 1536 : p.attn_wh + (size_t)(r - 768) * 1536;
    __half2* d = (__half2*)(p.gw1T + ((size_t)i << 2));
    d[0] = __halves2half2(__float2half(src[u]), __float2half(src[512 + u]));
    d[1] = __halves2half2(__float2half(src[1024 + u]), __float2half(0.f));
  }
  for (int i = t0; i < 1536 * 512; i += gsz) {
    int r = i >> 9, u = i & 511;
    const float* src = (r < 1024) ? p.out_wi + (size_t)r * 1536 : p.out_wh + (size_t)(r - 1024) * 1536;
    __half2* d = (__half2*)(p.gw2T + ((size_t)i << 2));
    d[0] = __halves2half2(__float2half(src[u]), __float2half(src[512 + u]));
    d[1] = __halves2half2(__float2half(src[1024 + u]), __float2half(0.f));
  }
  for (int i = t0; i < 512 * 512; i += gsz) {
    int k = i >> 9, a = i & 511;
    p.qwT[(size_t)a * 512 + k] = __float2half(p.q_w[(size_t)k * 512 + a]);
  }
  for (int i = t0; i < 1024 * 128; i += gsz) {
    int k = i >> 7, m = i & 127;
    p.decT[(size_t)m * 1024 + k] = __float2half(p.dec_w[(size_t)k * 128 + m]);
  }
  for (int i = t0; i < 1024; i += gsz) p.gateh[i] = __float2half(p.gate_w[i]);
  for (int i = t0; i < 16384; i += gsz) p.locwh[i] = __float2half(p.loc_w[i]);
  for (int i = t0; i < 128 * 256; i += gsz) {
    int m = i >> 8, pc = i & 255;
    p.pre1T[(size_t)pc * 128 + m] = __float2half(p.pre_w1[(size_t)m * 256 + pc]);
  }
  for (int i = t0; i < 256 * 256; i += gsz) {
    int k = i >> 8, pc = i & 255;
    p.pre2T[(size_t)pc * 256 + k] = __float2half(p.pre_w2[(size_t)k * 256 + pc]);
  }
  for (int i = t0; i < 106496; i += gsz) p.stateZ[i] = 0.f;
  for (int i = t0; i < 16384; i += gsz) p.ctxacc[i] = 0.f;
  for (int i = t0; i < 16384; i += gsz) p.ctxacc2[i] = 0.f;
  for (int i = t0; i < 2048; i += gsz) p.hAdone[i] = 0;   // whole flag region
  for (int i = t0; i < 12800; i += gsz) {
    int b = i / 400, t = i - b * 400;
    p.out_mask[i] = (t > p.mel_lens[b]) ? 1.f : 0.f;
  }
}

struct SMemMega {
  __half keysL[64 * 512];   // persistent P2 keys tile (64 KB)
  float ctxL[4][520];       // persistent ctx
  float hA2[4][520];        // persistent hA_next (staged in P2 tail)
  float hO2[4][520];        // persistent hO_prev (staged early in P1f)
  float invZ[4];
  union {
    struct { float x[4][264]; float4 part4[16][64]; } gr;
    struct { float locS[64][33]; float aw[94]; float ac[94]; float hA_s[512];
             float qS[512]; float qp2[16][64]; float cpred[8][512]; float eS[64]; } s3;
    struct { float xh[1024]; float red[1024]; float mel[128]; float p1[256]; } s6;
  } u;
};

// GRU partial accumulation over interleaved rows r = ks + 16*j, j in [j0,j1).
__device__ __forceinline__ void gchunk(const uint2* __restrict__ w,
                                       const float* __restrict__ x, int ks,
                                       int j0, int j1,
                                       float& a0, float& a1, float& a2) {
#pragma unroll 8
  for (int j = j0; j < j1; ++j) {
    uint2 wv = w[(size_t)j << 13];          // + j*16 rows * 512
    float xv = x[ks + (j << 4)];
    float2 f0 = cvt2(wv.x);
    float nf = cvt2(wv.y).x;
    a0 = fmaf(xv, f0.x, a0);
    a1 = fmaf(xv, f0.y, a1);
    a2 = fmaf(xv, nf, a2);
  }
}

__global__ __launch_bounds__(NTHR) void mega(Params p) {
  __shared__ SMemMega sm;
  const int blk = blockIdx.x, tid = threadIdx.x;
  const int ug = blk & 31, bg = blk >> 5, b0 = bg * 4;       // GRU identity
  const int bS = blk & 31, t8 = blk >> 5, t0g = t8 << 6;     // attention identity
  const int bgS = bS >> 2;                                   // bg owning batch bS

  const int u_ = tid & 15, b2_ = (tid >> 4) & 3, ks_ = tid >> 6;
  const int uG_ = (ug << 4) + u_;
  const uint2* w1 = (const uint2*)p.gw1T + ((size_t)ks_ << 9) + uG_;
  const uint2* w2 = (const uint2*)p.gw2T + ((size_t)ks_ << 9) + uG_;

  // ---- one-time: load keys tile into LDS, zero persistent LDS ----
  {
    const uint4* src = (const uint4*)(p.hkeys + (((size_t)(bS << 9) + t0g) << 9));
    uint4* dst = (uint4*)sm.keysL;
    for (int i = tid; i < 4096; i += NTHR) dst[i] = src[i];
    for (int i = tid; i < 2048; i += NTHR) {
      sm.ctxL[i >> 9][i & 511] = 0.f;
      sm.hA2[i >> 9][i & 511] = 0.f;
      sm.hO2[i >> 9][i & 511] = 0.f;
    }
  }
  __syncthreads();

  // GRU1 partial accumulators carried from P3 (prev step) into P1f (this step).
  float g1r = 0.f, g1z = 0.f, g1ni = 0.f, g1nh = 0.f;

#pragma clang loop unroll(disable)
  for (int step = 0; step < 400; step++) {
    const int par = step & 1;
    float* hA_prev = p.hA + par * 16384;
    float* hA_next = p.hA + (par ^ 1) * 16384;
    float* hO_prev = p.hO + par * 16384;
    float* hO_next = p.hO + (par ^ 1) * 16384;
    float* cCur = par ? p.ctxacc2 : p.ctxacc;
    float* cNxt = par ? p.ctxacc : p.ctxacc2;

    // GRU2 partial accumulators for THIS step
    float r2 = 0.f, z2 = 0.f, ni2 = 0.f, nh2 = 0.f;

    // ======== P1f: hoisted hO-part + GRU1 finish (decin rows) + hA ========
    {
      // hO_prev is published by done(s-1), two hops back -> near-instant wait.
      if (step > 0) {
        if (tid == 0) {
          while (ldai(&p.done[bg * 16]) < 32 * step)
            __builtin_amdgcn_s_sleep(2);
        }
        __syncthreads();
      }
      for (int i = tid; i < 2048; i += NTHR)
        sm.hO2[i >> 9][i & 511] = lda(&hO_prev[((b0 + (i >> 9)) << 9) + (i & 511)]);
      __syncthreads();
      // GRU2 hO-part (rows 1024..1535): overlaps previous step's S6 tail
      gchunk(w2, &sm.hO2[b2_][0] - 1024, ks_, 64, 96, r2, z2, nh2);
      // decin produced by S6(s-1): the real gate
      if (step > 0) {
        if (tid == 0) {
          while (ldai(&p.done2[bg * 16]) < 48 * step)
            __builtin_amdgcn_s_sleep(2);
        }
        __syncthreads();
      }
      for (int i = tid; i < 1024; i += NTHR)
        sm.u.gr.x[i >> 8][i & 255] = lda(&p.decin[((b0 + (i >> 8)) << 8) + (i & 255)]);
      __syncthreads();
      gchunk(w1, &sm.u.gr.x[b2_][0], ks_, 0, 16, g1r, g1z, g1ni);  // decin rows 0..255
      sm.u.gr.part4[ks_][(u_ << 2) + b2_] = make_float4(g1r, g1z, g1ni, g1nh);
      __syncthreads();
      if (tid < 64) {
        int uu = tid >> 2, bb2 = tid & 3;
        float4 s = make_float4(0.f, 0.f, 0.f, 0.f);
#pragma unroll
        for (int l = 0; l < 16; l++) {
          float4 v = sm.u.gr.part4[l][(uu << 2) + bb2];
          s.x += v.x; s.y += v.y; s.z += v.z; s.w += v.w;
        }
        int uGf = (ug << 4) + uu;
        float r = fast_sigmoid(s.x + p.attn_bi[uGf] + p.attn_bh[uGf]);
        float z = fast_sigmoid(s.y + p.attn_bi[512 + uGf] + p.attn_bh[512 + uGf]);
        float n = fast_tanh(s.z + p.attn_bi[1024 + uGf] + r * (s.w + p.attn_bh[1024 + uGf]));
        float hv = lda(&hA_prev[((b0 + bb2) << 9) + uGf]);
        sta(&hA_next[((b0 + bb2) << 9) + uGf], (1.f - z) * n + z * hv);
      }
      asm volatile("s_waitcnt vmcnt(0)" ::: "memory");
      if (tid == 0) atomicAdd(&p.hAdone[bg * 16], 1);   // 32/step per bg
    }

    // ======== P2: pre-wait staging/conv + q-slice + loc-acc + score + ctx ========
    {
      __syncthreads();   // union gr -> s3 transition
      for (int j = tid; j < 94; j += NTHR) {
        int pp = t0g - 15 + j;
        bool ok = (unsigned)pp < 512u;
        sm.u.s3.aw[j] = ok ? lda(&p.attw[(bS << 9) + pp]) : 0.f;
        sm.u.s3.ac[j] = ok ? lda(&p.attcum[(bS << 9) + pp]) : 0.f;
      }
      if (t8 == 0) {
        for (int i = tid; i < 512; i += NTHR) sta(&cNxt[(bS << 9) + i], 0.f);
      }
      __syncthreads();
      const int tlen = p.text_lens[bS];
      for (int i = tid; i < 2048; i += NTHR) {
        int tt = i >> 5, f = i & 31;
        const float* w0 = p.conv_w + f * 62;
        float a = 0.f;
#pragma unroll
        for (int k = 0; k < 31; k++)
          a = fmaf(w0[k], sm.u.s3.aw[tt + k], fmaf(w0[31 + k], sm.u.s3.ac[tt + k], a));
        sm.u.s3.locS[tt][f] = a;
      }
      if (tid == 0) {
        while (ldai(&p.hAdone[bgS * 16]) < 32 * (step + 1))
          __builtin_amdgcn_s_sleep(2);
      }
      __syncthreads();
      if (tid < 512) sm.u.s3.hA_s[tid] = lda(&hA_next[(bS << 9) + tid]);
      __syncthreads();
      // --- q-slice GEMV: a in [t0g, t0g+64), k split over 16 groups ---
      {
        int a = tid & 63, ks = tid >> 6;   // ks in 0..15
        const HU4* qp = (const HU4*)(p.qwT + (size_t)(t0g + a) * 512 + ks * 32);
        float q0 = 0.f, q1 = 0.f;
#pragma unroll
        for (int it = 0; it < 4; it++) {
          HU4 raw = qp[it];
          int kb = ks * 32 + it * 8;
#pragma unroll
          for (int h2 = 0; h2 < 4; h2++) {
            float2 w = __half22float2(raw.h[h2]);
            q0 = fmaf(sm.u.s3.hA_s[kb + h2 * 2], w.x, q0);
            q1 = fmaf(sm.u.s3.hA_s[kb + h2 * 2 + 1], w.y, q1);
          }
        }
        sm.u.s3.qp2[ks][a] = q0 + q1;
      }
      __syncthreads();
      if (tid < 64) {
        float s = 0.f;
#pragma unroll
        for (int l = 0; l < 16; l++) s += sm.u.s3.qp2[l][tid];
        sta(&p.qbuf[(bS << 9) + t0g + tid], s + p.loc_b[t0g + tid]);
      }
      if (tid == 0) {
        asm volatile("s_waitcnt vmcnt(0)" ::: "memory");
        atomicAdd(&p.qdone[bS * 16], 1);
      }
      // --- loc-only score accumulation (overlaps other blocks' q-slices) ---
      const int lane = tid & 63, wv = tid >> 6;
      float acc[4][8] = {};
#pragma unroll 4
      for (int f = 0; f < 32; f++) {
        HU4 rw; rw.u = *(const uint4*)(p.locwh + (size_t)f * 512 + lane * 8);
        float2 w0 = __half22float2(rw.h[0]), w1 = __half22float2(rw.h[1]);
        float2 w2v = __half22float2(rw.h[2]), w3 = __half22float2(rw.h[3]);
#pragma unroll
        for (int j = 0; j < 4; j++) {
          float lf = sm.u.s3.locS[wv * 4 + j][f];
          acc[j][0] = fmaf(lf, w0.x, acc[j][0]); acc[j][1] = fmaf(lf, w0.y, acc[j][1]);
          acc[j][2] = fmaf(lf, w1.x, acc[j][2]); acc[j][3] = fmaf(lf, w1.y, acc[j][3]);
          acc[j][4] = fmaf(lf, w2v.x, acc[j][4]); acc[j][5] = fmaf(lf, w2v.y, acc[j][5]);
          acc[j][6] = fmaf(lf, w3.x, acc[j][6]); acc[j][7] = fmaf(lf, w3.y, acc[j][7]);
        }
      }
      if (tid == 0) {
        while (ldai(&p.qdone[bS * 16]) < 8 * (step + 1))
          __builtin_amdgcn_s_sleep(2);
      }
      __syncthreads();
      if (tid < 512) sm.u.s3.qS[tid] = lda(&p.qbuf[(bS << 9) + tid]);
      __syncthreads();
      float4 qA = *(const float4*)&sm.u.s3.qS[lane * 8];
      float4 qB = *(const float4*)&sm.u.s3.qS[lane * 8 + 4];
#pragma unroll
      for (int j = 0; j < 4; j++) {
        int tL = wv * 4 + j;
        HU4 raw; raw.u = *(const uint4*)&sm.keysL[tL * 512 + lane * 8];
        float2 k0 = __half22float2(raw.h[0]), k1 = __half22float2(raw.h[1]);
        float2 k2 = __half22float2(raw.h[2]), k3 = __half22float2(raw.h[3]);
        acc[j][0] += qA.x + k0.x; acc[j][1] += qA.y + k0.y;
        acc[j][2] += qA.z + k1.x; acc[j][3] += qA.w + k1.y;
        acc[j][4] += qB.x + k2.x; acc[j][5] += qB.y + k2.y;
        acc[j][6] += qB.z + k3.x; acc[j][7] += qB.w + k3.y;
      }
      float4 sA = *(const float4*)(p.score_w + lane * 8);
      float4 sB = *(const float4*)(p.score_w + lane * 8 + 4);
      float sbias = p.score_b[0];
      float e_reg[4];
#pragma unroll
      for (int j = 0; j < 4; j++) {
        float pv = fast_tanh(acc[j][0]) * sA.x + fast_tanh(acc[j][1]) * sA.y +
                   fast_tanh(acc[j][2]) * sA.z + fast_tanh(acc[j][3]) * sA.w +
                   fast_tanh(acc[j][4]) * sB.x + fast_tanh(acc[j][5]) * sB.y +
                   fast_tanh(acc[j][6]) * sB.z + fast_tanh(acc[j][7]) * sB.w;
#pragma unroll
        for (int off = 32; off > 0; off >>= 1) pv += __shfl_xor(pv, off, 64);
        int t = t0g + wv * 4 + j;
        e_reg[j] = (t > tlen) ? 0.f : __expf(pv + sbias);
      }
      if (lane == 0) {
#pragma unroll
        for (int j = 0; j < 4; j++) sm.u.s3.eS[wv * 4 + j] = e_reg[j];
      }
      float cp[8] = {0.f, 0.f, 0.f, 0.f, 0.f, 0.f, 0.f, 0.f};
#pragma unroll
      for (int j = 0; j < 4; j++) {
        int tL = wv * 4 + j;
        HU4 raw; raw.u = *(const uint4*)&sm.keysL[tL * 512 + lane * 8];
        float2 k0 = __half22float2(raw.h[0]), k1 = __half22float2(raw.h[1]);
        float2 k2 = __half22float2(raw.h[2]), k3 = __half22float2(raw.h[3]);
        float e = e_reg[j];
        cp[0] = fmaf(e, k0.x, cp[0]); cp[1] = fmaf(e, k0.y, cp[1]);
        cp[2] = fmaf(e, k1.x, cp[2]); cp[3] = fmaf(e, k1.y, cp[3]);
        cp[4] = fmaf(e, k2.x, cp[4]); cp[5] = fmaf(e, k2.y, cp[5]);
        cp[6] = fmaf(e, k3.x, cp[6]); cp[7] = fmaf(e, k3.y, cp[7]);
      }
      __syncthreads();
      if (wv < 8) {
        float4* r0 = (float4*)&sm.u.s3.cpred[wv][lane * 8];
        r0[0] = make_float4(cp[0], cp[1], cp[2], cp[3]);
        r0[1] = make_float4(cp[4], cp[5], cp[6], cp[7]);
      }
      __syncthreads();
      if (wv >= 8) {
        float* r0 = &sm.u.s3.cpred[wv - 8][lane * 8];
#pragma unroll
        for (int i = 0; i < 8; i++) r0[i] += cp[i];
      }
      __syncthreads();
      if (tid < 512) {
        float s = 0.f;
#pragma unroll
        for (int j = 0; j < 8; j++) s += sm.u.s3.cpred[j][tid];
        atomicAdd(&cCur[(bS << 9) + tid], s);
      }
      if (tid < 64) {
        float e = sm.u.s3.eS[tid];
        sta(&p.ebuf[(bS << 9) + t0g + tid], e);
        float z = e;
#pragma unroll
        for (int off = 32; off > 0; off >>= 1) z += __shfl_xor(z, off, 64);
        if (tid == 0) sta(&p.zpart[bS * 8 + t8], z);
      }
      if (tid < 512 && (tid & 63) == 0) {
        asm volatile("s_waitcnt vmcnt(0)" ::: "memory");
        atomicAdd(&p.zdone[bgS * 16], 1);   // target 256 per bg per step
      }
      // ---- stage hA2 (own bg) + GRU2 hA-part ----
      if (tid == 0) {
        while (ldai(&p.hAdone[bg * 16]) < 32 * (step + 1))
          __builtin_amdgcn_s_sleep(2);
      }
      __syncthreads();
      for (int i = tid; i < 2048; i += NTHR)
        sm.hA2[i >> 9][i & 511] = lda(&hA_next[((b0 + (i >> 9)) << 9) + (i & 511)]);
      __syncthreads();
      gchunk(w2, &sm.hA2[b2_][0], ks_, 0, 32, r2, z2, ni2);   // rows 0..511
    }

    // ======== P3: ctx + GRU2 finish + S6/attw + GRU1-pre ========
    {
      if (tid == 0) {
        while (ldai(&p.zdone[bg * 16]) < 256 * (step + 1))
          __builtin_amdgcn_s_sleep(2);
      }
      __syncthreads();
      if (tid < 4) {
        float Z = 0.f;
#pragma unroll
        for (int j = 0; j < 8; j++) Z += lda(&p.zpart[(b0 + tid) * 8 + j]);
        sm.invZ[tid] = fast_rcp(Z);
      }
      __syncthreads();
      for (int i = tid; i < 2048; i += NTHR) {
        int b2 = i >> 9, a = i & 511;
        sm.ctxL[b2][a] = lda(&cCur[((b0 + b2) << 9) + a]) * sm.invZ[b2];
      }
      __syncthreads();
      gchunk(w2, &sm.ctxL[b2_][0] - 512, ks_, 32, 64, r2, z2, ni2);  // ctx rows
      sm.u.gr.part4[ks_][(u_ << 2) + b2_] = make_float4(r2, z2, ni2, nh2);
      __syncthreads();
      if (tid < 64) {
        int uu = tid >> 2, bb2 = tid & 3;
        float4 s = make_float4(0.f, 0.f, 0.f, 0.f);
#pragma unroll
        for (int l = 0; l < 16; l++) {
          float4 v = sm.u.gr.part4[l][(uu << 2) + bb2];
          s.x += v.x; s.y += v.y; s.z += v.z; s.w += v.w;
        }
        int uGf = (ug << 4) + uu;
        float r = fast_sigmoid(s.x + p.out_bi[uGf] + p.out_bh[uGf]);
        float z = fast_sigmoid(s.y + p.out_bi[512 + uGf] + p.out_bh[512 + uGf]);
        float n = fast_tanh(s.z + p.out_bi[1024 + uGf] + r * (s.w + p.out_bh[1024 + uGf]));
        float hv = sm.hO2[bb2][uGf];
        sta(&hO_next[((b0 + bb2) << 9) + uGf], (1.f - z) * n + z * hv);
      }
      asm volatile("s_waitcnt vmcnt(0)" ::: "memory");
      if (tid == 0) atomicAdd(&p.done[bg * 16], 1);   // 32/step per bg
      // ---- S6 (ug<4) / attw (ug in [4,8)) FIRST; GRU1-pre after ----
      if (ug < 4) {
        const int bb = b0 + ug;
        if (tid == 0) {
          while (ldai(&p.done[bg * 16]) < 32 * (step + 1))
            __builtin_amdgcn_s_sleep(2);
        }
        __syncthreads();
        sm.u.s6.xh[tid] = (tid < 512) ? lda(&hO_next[(bb << 9) + tid])
                                      : sm.ctxL[ug][tid - 512];
        __syncthreads();
        bool masked = step > p.mel_lens[bb];
        {
          int m = tid & 127, ks = tid >> 7;
          const HU4* dp = (const HU4*)(p.decT + (size_t)m * 1024 + ks * 128);
          float a = 0.f;
#pragma unroll 4
          for (int it = 0; it < 16; it++) {
            HU4 raw = dp[it];
            int kb = ks * 128 + it * 8;
#pragma unroll
            for (int h2 = 0; h2 < 4; h2++) {
              float2 w = __half22float2(raw.h[h2]);
              a = fmaf(sm.u.s6.xh[kb + h2 * 2], w.x, a);
              a = fmaf(sm.u.s6.xh[kb + h2 * 2 + 1], w.y, a);
            }
          }
          sm.u.s6.red[tid] = a;
        }
        __syncthreads();
        if (tid < 128) {
          float mv = p.dec_b[tid];
#pragma unroll
          for (int j = 0; j < 8; j++) mv += sm.u.s6.red[tid + j * 128];
          sm.u.s6.mel[tid] = mv;
          ntst(&p.out_mel[(size_t)bb * 51200 + (size_t)step * 128 + tid], masked ? 0.f : mv);
        }
        __syncthreads();
        sm.u.s6.red[tid] = sm.u.s6.xh[tid] * __half2float(p.gateh[tid]);
        __syncthreads();
        if (tid < 64) {
          float g = 0.f;
#pragma unroll
          for (int j = 0; j < 16; j++) g += sm.u.s6.red[tid + j * 64];
#pragma unroll
          for (int off = 32; off > 0; off >>= 1) g += __shfl_xor(g, off, 64);
          if (tid == 0) ntst(&p.out_gate[bb * 400 + step], masked ? 1000.f : (g + p.gate_b[0]));
        }
        __syncthreads();
        {
          int pc = tid & 255, ks = tid >> 8;
          const HU4* wp = (const HU4*)(p.pre1T + (size_t)pc * 128 + ks * 32);
          float a = 0.f;
#pragma unroll
          for (int it = 0; it < 4; it++) {
            HU4 raw = wp[it];
            int kb = ks * 32 + it * 8;
#pragma unroll
            for (int h2 = 0; h2 < 4; h2++) {
              float2 w = __half22float2(raw.h[h2]);
              a = fmaf(sm.u.s6.mel[kb + h2 * 2], w.x, a);
              a = fmaf(sm.u.s6.mel[kb + h2 * 2 + 1], w.y, a);
            }
          }
          sm.u.s6.red[tid] = a;
        }
        __syncthreads();
        if (tid < 256) {
          float a = sm.u.s6.red[tid] + sm.u.s6.red[tid + 256] +
                    sm.u.s6.red[tid + 512] + sm.u.s6.red[tid + 768];
          sm.u.s6.p1[tid] = fmaxf(a, 0.f);
        }
        __syncthreads();
        {
          int pc = tid & 255, ks = tid >> 8;
          const HU4* wp = (const HU4*)(p.pre2T + (size_t)pc * 256 + ks * 64);
          float a = 0.f;
#pragma unroll
          for (int it = 0; it < 8; it++) {
            HU4 raw = wp[it];
            int kb = ks * 64 + it * 8;
#pragma unroll
            for (int h2 = 0; h2 < 4; h2++) {
              float2 w = __half22float2(raw.h[h2]);
              a = fmaf(sm.u.s6.p1[kb + h2 * 2], w.x, a);
              a = fmaf(sm.u.s6.p1[kb + h2 * 2 + 1], w.y, a);
            }
          }
          sm.u.s6.red[tid] = a;
        }
        __syncthreads();
        if (tid < 256) {
          float a = sm.u.s6.red[tid] + sm.u.s6.red[tid + 256] +
                    sm.u.s6.red[tid + 512] + sm.u.s6.red[tid + 768];
          sta(&p.decin[(bb << 8) + tid], fmaxf(a, 0.f));
        }
        if (tid < 256 && (tid & 63) == 0) {
          asm volatile("s_waitcnt vmcnt(0)" ::: "memory");
          atomicAdd(&p.done2[bg * 16], 1);   // 4 incr/block x 4 blocks = 16
        }
      } else if (ug < 8) {
        // ---- attw/attcum update for batch b0+(ug-4): parallel with S6 ----
        const int bj = ug - 4, bb = b0 + bj;
        if (tid < 512) {
          float v = lda(&p.ebuf[(bb << 9) + tid]) * sm.invZ[bj];
          sta(&p.attw[(bb << 9) + tid], v);
          float oc = lda(&p.attcum[(bb << 9) + tid]);
          sta(&p.attcum[(bb << 9) + tid], oc + v);
          ntst(&p.out_attn[(size_t)bb * 204800 + (size_t)step * 512 + tid], v);
        }
        if (tid < 512 && (tid & 63) == 0) {
          asm volatile("s_waitcnt vmcnt(0)" ::: "memory");
          atomicAdd(&p.done2[bg * 16], 1);   // 8 incr/block x 4 blocks = 32
        }
      }
      // done2 target: 16 (S6) + 32 (attw) = 48 per bg per step
      // ---- GRU1 pre-accumulation for NEXT step (off the critical tail) ----
      g1r = 0.f; g1z = 0.f; g1ni = 0.f; g1nh = 0.f;
      if (step < 399) {
        gchunk(w1, &sm.ctxL[b2_][0] - 256, ks_, 16, 48, g1r, g1z, g1ni);
        gchunk(w1, &sm.hA2[b2_][0] - 768, ks_, 48, 80, g1r, g1z, g1nh);
      }
    }
  }
}

extern "C" void kernel_launch(void* const* d_in, const int* in_sizes, int n_in,
                              void* d_out, int out_size, void* d_ws, size_t ws_size,
                              hipStream_t stream) {
  Params p;
  p.enc       = (const float*)d_in[0];
  p.text_lens = (const int*)d_in[2];
  p.mel_lens  = (const int*)d_in[3];
  p.pre_w1    = (const float*)d_in[5];
  p.pre_w2    = (const float*)d_in[6];
  p.attn_wi   = (const float*)d_in[7];
  p.attn_wh   = (const float*)d_in[8];
  p.attn_bi   = (const float*)d_in[9];
  p.attn_bh   = (const float*)d_in[10];
  p.q_w       = (const float*)d_in[11];
  p.k_w       = (const float*)d_in[12];
  p.score_w   = (const float*)d_in[13];
  p.score_b   = (const float*)d_in[14];
  p.conv_w    = (const float*)d_in[15];
  p.loc_w     = (const float*)d_in[16];
  p.loc_b     = (const float*)d_in[17];
  p.out_wi    = (const float*)d_in[18];
  p.out_wh    = (const float*)d_in[19];
  p.out_bi    = (const float*)d_in[20];
  p.out_bh    = (const float*)d_in[21];
  p.dec_w     = (const float*)d_in[22];
  p.dec_b     = (const float*)d_in[23];
  p.gate_w    = (const float*)d_in[24];
  p.gate_b    = (const float*)d_in[25];

  float* ws = (float*)d_ws;
  p.hkeys  = (__half*)(ws);                    // 8,388,608 halfs
  p.gw1T   = (__half*)(ws + 4194304);
  p.gw2T   = (__half*)(ws + 5505024);
  p.decT   = (__half*)(ws + 7077888);
  p.pre1T  = (__half*)(ws + 7143424);
  p.pre2T  = (__half*)(ws + 7159808);
  p.gateh  = (__half*)(ws + 7192576);
  p.locwh  = (__half*)(ws + 7193088);
  p.qwT    = (__half*)(ws + 7201280);
  p.hA     = ws + 7332352;
  p.hO     = ws + 7365120;
  p.attw   = ws + 7397888;
  p.attcum = ws + 7414272;
  p.decin  = ws + 7430656;
  p.stateZ = p.hA;                             // zero region: hA,hO,attw,attcum,decin = 106,496
  p.ebuf   = ws + 7438848;
  p.zpart  = ws + 7455232;
  p.ctxacc = ws + 7455488;                     // 16384
  p.ctxacc2 = ws + 7472416;                    // 16384
  int* fb  = (int*)(ws + 7488800);             // 2048-int flag region
  p.hAdone = fb;                               // per-bg x16
  p.zdone  = fb + 128;                         // per-bg x16
  p.done   = fb + 256;                         // per-bg x16
  p.done2  = fb + 384;                         // per-bg x16
  p.qdone  = fb + 512;                         // per-batch x16
  p.qbuf   = ws + 7490848;                     // 16384 floats
  float* out = (float*)d_out;
  p.out_mel  = out;
  p.out_gate = out + 1638400;
  p.out_attn = out + 1651200;
  p.out_mask = out + 8204800;

  k_repack<<<2048, 256, 0, stream>>>(p);
  k_keys<<<dim3(128, 8), 512, 0, stream>>>(p);
  void* args[] = { (void*)&p };
  hipLaunchCooperativeKernel((const void*)mega, dim3(NBLK), dim3(NTHR), args, 0, stream);
}